// Round 1
// baseline (57.246 us; speedup 1.0000x reference)
//
#include <hip/hip_runtime.h>
#include <math.h>

#define BATCH 8
#define NPTS 4096
#define JCHUNK 512
#define NJC (NPTS / JCHUNK)   /* 8  */
#define ICHUNK 256
#define NIC (NPTS / ICHUNK)   /* 16 */

// Workspace layout (floats):
//   [0,             BATCH*NPTS*2)              scaled coordinates (x*s, y*s)
//   [BATCH*NPTS*2,  BATCH*NPTS*3)              scaled weights (w * norm)
//   [BATCH*NPTS*3,  BATCH*NPTS*3 + NJC*BATCH*NPTS)  per-j-chunk partial sums
// Total = 11 * 32768 * 4 B = 1.44 MB

__global__ __launch_bounds__(256)
void kde_prep(const float* __restrict__ w, const float* __restrict__ c,
              const float* __restrict__ sigma,
              float* __restrict__ sc, float* __restrict__ sw) {
    int idx = blockIdx.x * 256 + threadIdx.x;       // 0 .. BATCH*NPTS-1
    float sg      = sigma[0];
    float inv2s2  = 1.0f / (2.0f * sg * sg);
    // exp(-d2*inv2s2) = exp2(-d2*inv2s2*log2(e)); fold into coord scaling
    float s       = sqrtf(inv2s2 * 1.4426950408889634f);
    float norm    = inv2s2 * 0.3183098861837907f;   // 1/(2*pi*sg^2)
    float2 cc = ((const float2*)c)[idx];
    ((float2*)sc)[idx] = make_float2(cc.x * s, cc.y * s);
    sw[idx] = w[idx] * norm;
}

__global__ __launch_bounds__(256)
void kde_main(const float* __restrict__ sc, const float* __restrict__ sw,
              float* __restrict__ part) {
    __shared__ float xs[JCHUNK];
    __shared__ float ys[JCHUNK];
    __shared__ float wl[JCHUNK];

    int b  = blockIdx.x;
    int ic = blockIdx.y;
    int jc = blockIdx.z;
    int j0 = jc * JCHUNK;

    for (int t = threadIdx.x; t < JCHUNK; t += 256) {
        float2 cj = ((const float2*)sc)[b * NPTS + j0 + t];
        xs[t] = cj.x;
        ys[t] = cj.y;
        wl[t] = sw[b * NPTS + j0 + t];
    }
    __syncthreads();

    int i = ic * ICHUNK + threadIdx.x;
    float2 ci = ((const float2*)sc)[b * NPTS + i];

    float acc = 0.0f;
#pragma unroll 8
    for (int j = 0; j < JCHUNK; ++j) {
        float dx = ci.x - xs[j];
        float dy = ci.y - ys[j];
        float e  = -(dx * dx + dy * dy);        // fma with neg modifiers
        acc = fmaf(exp2f(e), wl[j], acc);       // v_exp_f32 + v_fmac
    }
    part[(jc * BATCH + b) * NPTS + i] = acc;
}

__global__ __launch_bounds__(256)
void kde_reduce(const float* __restrict__ part, float* __restrict__ out) {
    int idx = blockIdx.x * 256 + threadIdx.x;   // 0 .. BATCH*NPTS-1
    float s = 0.0f;
#pragma unroll
    for (int jc = 0; jc < NJC; ++jc)
        s += part[jc * BATCH * NPTS + idx];
    out[idx] = s;
}

extern "C" void kernel_launch(void* const* d_in, const int* in_sizes, int n_in,
                              void* d_out, int out_size, void* d_ws, size_t ws_size,
                              hipStream_t stream) {
    const float* w     = (const float*)d_in[0];   // [8,4096]
    const float* c     = (const float*)d_in[1];   // [8,4096,2]
    const float* sigma = (const float*)d_in[2];   // scalar
    float* out = (float*)d_out;                   // [8,4096]

    float* sc   = (float*)d_ws;                       // scaled coords
    float* sw   = sc + BATCH * NPTS * 2;              // scaled weights
    float* part = sw + BATCH * NPTS;                  // partials [NJC][B][N]

    kde_prep<<<(BATCH * NPTS) / 256, 256, 0, stream>>>(w, c, sigma, sc, sw);
    kde_main<<<dim3(BATCH, NIC, NJC), 256, 0, stream>>>(sc, sw, part);
    kde_reduce<<<(BATCH * NPTS) / 256, 256, 0, stream>>>(part, out);
}